// Round 13
// baseline (232.023 us; speedup 1.0000x reference)
//
#include <hip/hip_runtime.h>
#include <stdint.h>

// AttentionBlock: B=32, C=512, H=W=32 (N=1024), fp32 in/out.
//   cvt: Wq,Wk,Wv -> fp8 e4m3; Wo -> fp8 scaled by 2^22; bqk=[bq;bk] f32
//   transpose x -> Xt [B,N,C] fp8
//   QK = Xt*[Wq;Wk]^T + [bq;bk]  [B*N,1024] fp8  (256x128-tile gemm)
//   V  = Wv*Xt_b^T + bv          [B][C][N] fp8   (256x128-tile gemm)
//   H  = flash_attn fp8 (kv64, PV(t) interleaved with QK(t+1), 1 barrier/tile)
//   out = (Wo*2^22)*H_b^T * 2^-22 + bo + x   [B][C][N] fp32 (fp8 gemm 128^2)

#define CD 512
#define NSP 1024
#define SCALE_EXP2 0.06376339f   // C^-0.5 * log2(e)
#define WO_SCALE 4194304.0f      // 2^22
#define WO_INV   2.384185791015625e-7f

using f32x4  = __attribute__((ext_vector_type(4))) float;
typedef long i64v;               // 8 x fp8 operand for MFMA

__device__ __forceinline__ unsigned char f2f8(float f) {
    unsigned int r;
    asm("v_cvt_pk_fp8_f32 %0, %1, %1" : "=v"(r) : "v"(f));
    return (unsigned char)(r & 0xffu);
}
__device__ __forceinline__ unsigned int f4_to_f8x4(float a, float b, float c, float d) {
    unsigned int r = 0;
    asm("v_cvt_pk_fp8_f32 %0, %2, %3\n\t"
        "v_cvt_pk_fp8_f32 %0, %4, %5 op_sel:[0,0,1]"
        : "=v"(r) : "0"(r), "v"(a), "v"(b), "v"(c), "v"(d));
    return r;
}
__device__ __forceinline__ void gl_lds16(const void* g, void* l) {
    __builtin_amdgcn_global_load_lds(
        (const __attribute__((address_space(1))) void*)g,
        (__attribute__((address_space(3))) void*)l, 16, 0, 0);
}

// Wq,Wk,Wv,Wo -> fp8 (contiguous [4*512][512]; Wo scaled 2^22); bqk concat f32
__global__ __launch_bounds__(256) void cvt_all(
    const float* __restrict__ Wq, const float* __restrict__ Wk,
    const float* __restrict__ Wv, const float* __restrict__ Wo,
    const float* __restrict__ bq, const float* __restrict__ bk,
    unsigned char* __restrict__ w8, float* __restrict__ bqk)
{
    int idx = blockIdx.x * 256 + threadIdx.x;     // 0..1048575
    int which = idx >> 18, off = idx & 262143;
    const float* src = which == 0 ? Wq : which == 1 ? Wk : which == 2 ? Wv : Wo;
    float v = src[off] * (which == 3 ? WO_SCALE : 1.0f);
    w8[idx] = f2f8(v);
    if (idx < 1024) bqk[idx] = (idx < 512) ? bq[idx] : bk[idx - 512];
}

// x [B][C][N] f32 -> xt [B][N][C] fp8
__global__ __launch_bounds__(256) void transpose_x(const float* __restrict__ x,
                                                   unsigned char* __restrict__ xt) {
    __shared__ float t[32][33];
    int b = blockIdx.z;
    int n0 = blockIdx.x * 32, c0 = blockIdx.y * 32;
    const float* xb = x + (size_t)b * CD * NSP;
    unsigned char* xtb = xt + (size_t)b * NSP * CD;
    int tx = threadIdx.x, ty = threadIdx.y;
    #pragma unroll
    for (int i = 0; i < 4; ++i)
        t[ty + i * 8][tx] = xb[(size_t)(c0 + ty + i * 8) * NSP + n0 + tx];
    __syncthreads();
    #pragma unroll
    for (int i = 0; i < 4; ++i)
        xtb[(size_t)(n0 + ty + i * 8) * CD + c0 + tx] = f2f8(t[tx][ty + i * 8]);
}

// fp8 GEMM, 256(M)x128(N) tile, BK=64, 4 waves (each 64M x 128N), dbuf
// gl_lds16 staging, counted vmcnt. C fp8 (+bias).
template<int BIAS_MODE>
__global__ __launch_bounds__(256)
void gemm_bt8_256(const unsigned char* __restrict__ A,
                  const unsigned char* __restrict__ B,
                  unsigned char* __restrict__ C8,
                  const float* __restrict__ bias,
                  int K, int lda, int ldb, int ldc,
                  long sA, long sB, long sC)
{
    __shared__ __align__(16) unsigned char As[2][256 * 64];  // 32 KB
    __shared__ __align__(16) unsigned char Bs[2][128 * 64];  // 16 KB

    const int z = blockIdx.z;
    const unsigned char* Ab = A + (size_t)z * sA + (size_t)blockIdx.y * 256 * lda;
    const unsigned char* Bb = B + (size_t)z * sB + (size_t)blockIdx.x * 128 * ldb;

    const int t = threadIdx.x;
    const int lane = t & 63;
    const int wave = t >> 6;
    const int lr = lane & 15, lk = lane >> 4;

    f32x4 acc[4][8] = {};

    const int KT = K >> 6;
    auto stage = [&](int kt, int buf) {
        int k0 = kt << 6;
        #pragma unroll
        for (int i = 0; i < 4; ++i) {           // A: 4x16 rows/wave
            int rb = i * 64 + wave * 16;
            int row = rb + (lane >> 2);
            int src = (lane & 3) ^ ((row >> 1) & 3);
            gl_lds16(Ab + (size_t)row * lda + k0 + src * 16, &As[buf][rb * 64]);
        }
        #pragma unroll
        for (int i = 0; i < 2; ++i) {           // B: 2x16 rows/wave
            int rb = i * 64 + wave * 16;
            int row = rb + (lane >> 2);
            int src = (lane & 3) ^ ((row >> 1) & 3);
            gl_lds16(Bb + (size_t)row * ldb + k0 + src * 16, &Bs[buf][rb * 64]);
        }
    };
    stage(0, 0);
    for (int kt = 0; kt < KT; ++kt) {
        int cur = kt & 1;
        if (kt + 1 < KT) {
            stage(kt + 1, cur ^ 1);
            asm volatile("s_waitcnt vmcnt(6)" ::: "memory");
        } else {
            asm volatile("s_waitcnt vmcnt(0)" ::: "memory");
        }
        __builtin_amdgcn_s_barrier();
        const unsigned char* Ac = &As[cur][0];
        const unsigned char* Bc = &Bs[cur][0];
        #pragma unroll
        for (int kk = 0; kk < 2; ++kk) {
            int c16 = kk * 2 + (lk >> 1);
            int half = (lk & 1) * 8;
            i64v af[4], bfr[8];
            #pragma unroll
            for (int f = 0; f < 4; ++f) {
                int arow = wave * 64 + f * 16 + lr;
                af[f] = *(const i64v*)&Ac[arow * 64 + ((c16 ^ ((arow >> 1) & 3)) << 4) + half];
            }
            #pragma unroll
            for (int fn = 0; fn < 8; ++fn) {
                int brow = fn * 16 + lr;
                bfr[fn] = *(const i64v*)&Bc[brow * 64 + ((c16 ^ ((brow >> 1) & 3)) << 4) + half];
            }
            #pragma unroll
            for (int fm = 0; fm < 4; ++fm)
                #pragma unroll
                for (int fn = 0; fn < 8; ++fn)
                    acc[fm][fn] = __builtin_amdgcn_mfma_f32_16x16x32_fp8_fp8(
                        af[fm], bfr[fn], acc[fm][fn], 0, 0, 0);
        }
        asm volatile("s_waitcnt lgkmcnt(0)" ::: "memory");
        __builtin_amdgcn_s_barrier();
    }

    const int m0 = blockIdx.y * 256;
    const int n0 = blockIdx.x * 128;
    unsigned char* Cp = C8 + (size_t)z * sC;
    #pragma unroll
    for (int fm = 0; fm < 4; ++fm) {
        #pragma unroll
        for (int fn = 0; fn < 8; ++fn) {
            int col = n0 + fn * 16 + lr;                    // D col = lane&15
            int rowb = m0 + wave * 64 + fm * 16 + lk * 4;   // D row = 4*(lane>>4)+j
            #pragma unroll
            for (int j = 0; j < 4; ++j) {
                int row = rowb + j;
                float v = acc[fm][fn][j];
                if (BIAS_MODE == 1) v += bias[col];
                if (BIAS_MODE == 2) v += bias[row];
                Cp[(size_t)row * ldc + col] = f2f8(v);
            }
        }
    }
}

// fp8 GEMM 128x128 (out-projection): out = alpha*Wo8*H8^T + bias[row] + resid.
__global__ __launch_bounds__(256)
void gemm_bt8_out(const unsigned char* __restrict__ A,
                  const unsigned char* __restrict__ B,
                  float* __restrict__ Cf,
                  const float* __restrict__ bias,
                  const float* __restrict__ resid,
                  int K, int lda, int ldb, int ldc,
                  long sB, long sC, long sR, float alpha)
{
    __shared__ __align__(16) unsigned char As[2][128 * 64];
    __shared__ __align__(16) unsigned char Bs[2][128 * 64];

    const int z = blockIdx.z;
    const unsigned char* Ab = A + (size_t)blockIdx.y * 128 * lda;
    const unsigned char* Bb = B + (size_t)z * sB + (size_t)blockIdx.x * 128 * ldb;

    const int t = threadIdx.x;
    const int lane = t & 63;
    const int wave = t >> 6;
    const int wr = wave >> 1, wc = wave & 1;
    const int lr = lane & 15, lk = lane >> 4;

    f32x4 acc[4][4] = {};

    const int KT = K >> 6;
    auto stage = [&](int kt, int buf) {
        int k0 = kt << 6;
        #pragma unroll
        for (int i = 0; i < 2; ++i) {
            int rb = i * 64 + wave * 16;
            int row = rb + (lane >> 2);
            int src = (lane & 3) ^ ((row >> 1) & 3);
            gl_lds16(Ab + (size_t)row * lda + k0 + src * 16, &As[buf][rb * 64]);
            gl_lds16(Bb + (size_t)row * ldb + k0 + src * 16, &Bs[buf][rb * 64]);
        }
    };
    stage(0, 0);
    for (int kt = 0; kt < KT; ++kt) {
        int cur = kt & 1;
        if (kt + 1 < KT) {
            stage(kt + 1, cur ^ 1);
            asm volatile("s_waitcnt vmcnt(4)" ::: "memory");
        } else {
            asm volatile("s_waitcnt vmcnt(0)" ::: "memory");
        }
        __builtin_amdgcn_s_barrier();
        const unsigned char* Ac = &As[cur][0];
        const unsigned char* Bc = &Bs[cur][0];
        #pragma unroll
        for (int kk = 0; kk < 2; ++kk) {
            int c16 = kk * 2 + (lk >> 1);
            int half = (lk & 1) * 8;
            i64v af[4], bfr[4];
            #pragma unroll
            for (int f = 0; f < 4; ++f) {
                int arow = wr * 64 + f * 16 + lr;
                af[f] = *(const i64v*)&Ac[arow * 64 + ((c16 ^ ((arow >> 1) & 3)) << 4) + half];
                int brow = wc * 64 + f * 16 + lr;
                bfr[f] = *(const i64v*)&Bc[brow * 64 + ((c16 ^ ((brow >> 1) & 3)) << 4) + half];
            }
            #pragma unroll
            for (int fm = 0; fm < 4; ++fm)
                #pragma unroll
                for (int fn = 0; fn < 4; ++fn)
                    acc[fm][fn] = __builtin_amdgcn_mfma_f32_16x16x32_fp8_fp8(
                        af[fm], bfr[fn], acc[fm][fn], 0, 0, 0);
        }
        asm volatile("s_waitcnt lgkmcnt(0)" ::: "memory");
        __builtin_amdgcn_s_barrier();
    }

    const int m0 = blockIdx.y * 128;
    const int n0 = blockIdx.x * 128;
    float* Co = Cf + (size_t)z * sC;
    const float* rp = resid + (size_t)z * sR;
    #pragma unroll
    for (int fm = 0; fm < 4; ++fm) {
        #pragma unroll
        for (int fn = 0; fn < 4; ++fn) {
            int col = n0 + wc * 64 + fn * 16 + lr;
            int rowb = m0 + wr * 64 + fm * 16 + lk * 4;
            #pragma unroll
            for (int j = 0; j < 4; ++j) {
                int row = rowb + j;
                Co[(size_t)row * ldc + col] = acc[fm][fn][j] * alpha
                    + bias[row] + rp[(size_t)row * ldc + col];
            }
        }
    }
}

// Fused attention, fp8, kv-tile 64, 8 waves, grid 256. Per iteration the
// single barrier interval runs a FUSED 16-step loop: each step issues 4 PV(t)
// MFMAs (from Ps[cur],Vs[cur]) + 4 QK(t+1) MFMAs (from Ks[cur^1]) back-to-back
// (independent streams keep the matrix pipe fed through softmax/LDS latency),
// then softmax(t+1) -> Ps[cur^1]. Staging at iteration top, vmcnt(0) at end.
__global__ __launch_bounds__(512, 2)
void flash_attn(const unsigned char* __restrict__ Q,
                const unsigned char* __restrict__ Kg,
                const unsigned char* __restrict__ Vg,
                unsigned char* __restrict__ H)
{
    __shared__ __align__(16) unsigned char Ks[2][64 * 512];  // 64 KB
    __shared__ __align__(16) unsigned char Vs[2][512 * 64];  // 64 KB
    __shared__ __align__(16) unsigned char Ps[2][128 * 72];  // 18 KB
    __shared__ __align__(16) float Ls[2][128];
    __shared__ int flags[2];                                 // rescale epoch

    const int p = blockIdx.x;                // XCD-affinity decode
    const int b  = ((p >> 6) << 3) + (p & 7);
    const int qt = (p >> 3) & 7;

    const int tid = threadIdx.x;
    const int w = tid >> 6, lane = tid & 63;
    const int lr = lane & 15, lk = lane >> 4;
    const int q0 = qt * 128 + w * 16;

    // Q frags (B-operand): lane holds Q[q0+lr][st*32 + lk*8 + e], fp8
    i64v qf[16];
    const unsigned char* qp = Q + ((size_t)b * NSP + q0 + lr) * 1024 + lk * 8;
    #pragma unroll
    for (int st = 0; st < 16; ++st) qf[st] = *(const i64v*)(qp + st * 32);

    f32x4 o[8][4] = {};          // [qf2][cf]: q = qf2*16+4lk+j, c = w*64+cf*16+lr
    float m = -3.0e38f, l = 0.f;

    const unsigned char* Kb = Kg + (size_t)b * NSP * 1024;   // rows 1024B (Q|K)
    const unsigned char* Vb = Vg + (size_t)b * CD * 1024;

    auto stageK = [&](int t, int buf) {      // 64 rows x 512B; 8 rows/wave
        int kv0 = t * 64;
        #pragma unroll
        for (int i = 0; i < 4; ++i) {
            int rb = i * 16 + w * 2;
            int row = rb + (lane >> 5);
            int src = (lane & 31) ^ (row & 7);
            gl_lds16(Kb + (size_t)(kv0 + row) * 1024 + src * 16, &Ks[buf][rb * 512]);
        }
    };
    auto stageV = [&](int t, int buf) {      // 512 rows x 64B; 64 rows/wave
        int kv0 = t * 64;
        #pragma unroll
        for (int i = 0; i < 4; ++i) {
            int cb = i * 128 + w * 16;
            int c = cb + (lane >> 2);
            int src = (lane & 3) ^ ((c >> 1) & 3);
            gl_lds16(Vb + (size_t)c * 1024 + kv0 + src * 16, &Vs[buf][cb * 64]);
        }
    };

    // softmax + P-pack for tile tau (s = scaled scores^T, 16 vals for q=lr)
    auto softmax_pack = [&](int tau, f32x4* s) {
        const int pb = tau & 1;
        #pragma unroll
        for (int kvf = 0; kvf < 4; ++kvf)
            #pragma unroll
            for (int j = 0; j < 4; ++j) s[kvf][j] *= SCALE_EXP2;
        float pm = fmaxf(fmaxf(fmaxf(s[0][0], s[0][1]), fmaxf(s[0][2], s[0][3])),
                         fmaxf(fmaxf(s[1][0], s[1][1]), fmaxf(s[1][2], s[1][3])));
        pm = fmaxf(pm, fmaxf(fmaxf(fmaxf(s[2][0], s[2][1]), fmaxf(s[2][2], s[2][3])),
                             fmaxf(fmaxf(s[3][0], s[3][1]), fmaxf(s[3][2], s[3][3]))));
        pm = fmaxf(pm, __shfl_xor(pm, 16));
        pm = fmaxf(pm, __shfl_xor(pm, 32));
        bool ev = !__all(pm - m <= 8.0f);       // defer-max: P <= 2^8 < 448
        float mn = fmaxf(m, pm);
        float sc = ev ? exp2f(m - mn) : 1.0f;
        if (ev) { m = mn; l *= sc; }
        if (lk == 0) Ls[pb][w * 16 + lr] = sc;
        if (ev && lane == 0) flags[pb] = tau;   // epoch flag
        float rs = 0.f;
        #pragma unroll
        for (int kvf = 0; kvf < 4; ++kvf)
            #pragma unroll
            for (int j = 0; j < 4; ++j) {
                s[kvf][j] = exp2f(s[kvf][j] - m);
                rs += s[kvf][j];
            }
        rs += __shfl_xor(rs, 16);
        rs += __shfl_xor(rs, 32);
        l += rs;
        #pragma unroll
        for (int kvf = 0; kvf < 4; ++kvf) {
            unsigned int pk = f4_to_f8x4(s[kvf][0], s[kvf][1], s[kvf][2], s[kvf][3]);
            *(unsigned int*)&Ps[pb][(w * 16 + lr) * 72 + kvf * 16 + lk * 4] = pk;
        }
    };

    auto rescale_o = [&](int pb) {
        #pragma unroll
        for (int qf2 = 0; qf2 < 8; ++qf2) {
            f32x4 scv = *(const f32x4*)&Ls[pb][qf2 * 16 + lk * 4];
            #pragma unroll
            for (int cf = 0; cf < 4; ++cf) {
                o[qf2][cf][0] *= scv[0]; o[qf2][cf][1] *= scv[1];
                o[qf2][cf][2] *= scv[2]; o[qf2][cf][3] *= scv[3];
            }
        }
    };

    if (tid == 0) { flags[0] = -1; flags[1] = -1; }
    stageK(0, 0); stageV(0, 0);
    asm volatile("s_waitcnt vmcnt(0) lgkmcnt(0)" ::: "memory");
    __builtin_amdgcn_s_barrier();
    stageK(1, 1);
    {   // prologue: QK(0) + softmax(0) -> Ps[0]
        f32x4 s[4] = {};
        const unsigned char* Kc = &Ks[0][0];
        #pragma unroll
        for (int st = 0; st < 16; ++st) {
            int c16 = st * 2 + (lk >> 1);
            int half = (lk & 1) * 8;
            #pragma unroll
            for (int kvf = 0; kvf < 4; ++kvf) {
                int row = kvf * 16 + lr;
                i64v kf = *(const i64v*)&Kc[row * 512 + ((c16 ^ (row & 7)) << 4) + half];
                s[kvf] = __builtin_amdgcn_mfma_f32_16x16x32_fp8_fp8(kf, qf[st], s[kvf], 0, 0, 0);
            }
        }
        softmax_pack(0, s);
    }
    asm volatile("s_waitcnt vmcnt(0) lgkmcnt(0)" ::: "memory");
    __builtin_amdgcn_s_barrier();               // P(0) visible; K(1) landed

    for (int t = 0; t < 15; ++t) {
        const int cur = t & 1;
        if (t < 14) stageK(t + 2, cur);         // Ks[cur]: readers drained at t-1
        stageV(t + 1, cur ^ 1);                 // Vs[cur^1]: readers drained at t-1
        if (flags[cur] == t) rescale_o(cur);

        // ---- fused: PV(t) interleaved with QK(t+1) MFMAs ----
        const unsigned char* Vc = &Vs[cur][0];
        const unsigned char* Pc = &Ps[cur][0];
        const unsigned char* Kc = &Ks[cur ^ 1][0];
        f32x4 s[4] = {};
        i64v vfr[4];
        __builtin_amdgcn_s_setprio(1);
        #pragma unroll
        for (int st = 0; st < 16; ++st) {
            const int ks = st >> 3;
            const int qf2 = st & 7;
            if ((st & 7) == 0) {                // reload V frags per ks-half
                int c16v = ks * 2 + (lk >> 1);
                int halfv = (lk & 1) * 8;
                #pragma unroll
                for (int cf = 0; cf < 4; ++cf) {
                    int c = w * 64 + cf * 16 + lr;
                    vfr[cf] = *(const i64v*)&Vc[c * 64 + ((c16v ^ ((c >> 1) & 3)) << 4) + halfv];
                }
            }
            i64v pa = *(const i64v*)&Pc[(qf2 * 16 + lr) * 72 + ks * 32 + lk * 8];
            int c16 = st * 2 + (lk >> 1);
            int half = (lk & 1) * 8;
            i64v kf[4];
            #pragma unroll
            for (int kvf = 0; kvf < 4; ++kvf) {
                int row = kvf * 16 + lr;
                kf[kvf] = *(const i64v*)&Kc[row * 512 + ((c16 ^ (row & 7)) << 4) + half];
            }
            #pragma unroll
            for (int cf = 0; cf < 4; ++cf)
                o[qf2][cf] = __builtin_amdgcn_mfma_f32_16x16x32_fp8_fp8(
                    pa, vfr[cf], o[qf2][cf], 0, 0, 0);
            #pragma unroll
            for (int kvf = 0; kvf < 4; ++kvf)
                s[kvf] = __builtin_amdgcn_mfma_f32_16x16x32_fp8_fp8(
                    kf[kvf], qf[st], s[kvf], 0, 0, 0);
        }
        __builtin_amdgcn_s_setprio(0);

        softmax_pack(t + 1, s);                 // -> Ps[cur^1]

        asm volatile("s_waitcnt vmcnt(0) lgkmcnt(0)" ::: "memory");
        __builtin_amdgcn_s_barrier();
    }

    // ---- tail t=15: PV only ----
    {
        const int cur = 1;
        if (flags[cur] == 15) rescale_o(cur);
        const unsigned char* Vc = &Vs[cur][0];
        const unsigned char* Pc = &Ps[cur][0];
        __builtin_amdgcn_s_setprio(1);
        #pragma unroll
        for (int ks = 0; ks < 2; ++ks) {
            int c16 = ks * 2 + (lk >> 1);
            int half = (lk & 1) * 8;
            i64v vfr[4];
            #pragma unroll
            for (int cf = 0; cf < 4; ++cf) {
                int c = w * 64 + cf * 16 + lr;
                vfr[cf] = *(const i64v*)&Vc[c * 64 + ((c16 ^ ((c >> 1) & 3)) << 4) + half];
            }
            #pragma unroll
            for (int qf2 = 0; qf2 < 8; ++qf2) {
                i64v pa = *(const i64v*)&Pc[(qf2 * 16 + lr) * 72 + ks * 32 + lk * 8];
                #pragma unroll
                for (int cf = 0; cf < 4; ++cf)
                    o[qf2][cf] = __builtin_amdgcn_mfma_f32_16x16x32_fp8_fp8(
                        pa, vfr[cf], o[qf2][cf], 0, 0, 0);
            }
        }
        __builtin_amdgcn_s_setprio(0);
        asm volatile("s_waitcnt lgkmcnt(0)" ::: "memory");
        __builtin_amdgcn_s_barrier();
    }

    // epilogue: 1/l per q-row via Ls[0], write H fp8
    if (lk == 0) Ls[0][w * 16 + lr] = 1.0f / l;
    asm volatile("s_waitcnt lgkmcnt(0)" ::: "memory");
    __builtin_amdgcn_s_barrier();
    unsigned char* Hp = H + ((size_t)b * NSP + qt * 128) * CD + w * 64;
    #pragma unroll
    for (int qf2 = 0; qf2 < 8; ++qf2) {
        f32x4 li = *(const f32x4*)&Ls[0][qf2 * 16 + lk * 4];
        #pragma unroll
        for (int cf = 0; cf < 4; ++cf) {
            #pragma unroll
            for (int j = 0; j < 4; ++j)
                Hp[(size_t)(qf2 * 16 + lk * 4 + j) * CD + cf * 16 + lr] =
                    f2f8(o[qf2][cf][j] * li[j]);
        }
    }
}

extern "C" void kernel_launch(void* const* d_in, const int* in_sizes, int n_in,
                              void* d_out, int out_size, void* d_ws, size_t ws_size,
                              hipStream_t stream)
{
    const float* x  = (const float*)d_in[0];
    const float* Wq = (const float*)d_in[1];
    const float* bq = (const float*)d_in[2];
    const float* Wk = (const float*)d_in[3];
    const float* bk = (const float*)d_in[4];
    const float* Wv = (const float*)d_in[5];
    const float* bv = (const float*)d_in[6];
    const float* Wo = (const float*)d_in[7];
    const float* bo = (const float*)d_in[8];
    float* out = (float*)d_out;

    unsigned char* w = (unsigned char*)d_ws;   // byte layout, 16B-aligned
    unsigned char* W8  = w;                     // Wq|Wk|Wv|Wo(x2^22) fp8, 1 MB
    float*         bqk = (float*)(w + 1048576); // 4 KB
    unsigned char* Xt8 = w + 1052672;           // [B][N][C] fp8, 16 MB
    unsigned char* QK8 = w + 17829888;          // [B][N][1024] fp8, 32 MB
    unsigned char* Vc8 = w + 51384320;          // [B][C][N] fp8, 16 MB
    unsigned char* H8  = w + 68161536;          // [B][N][C] fp8, 16 MB

    cvt_all<<<4096, 256, 0, stream>>>(Wq, Wk, Wv, Wo, bq, bk, W8, bqk);
    transpose_x<<<dim3(32, 16, 32), dim3(32, 8), 0, stream>>>(x, Xt8);

    // QK = Xt * [Wq;Wk]^T + [bq;bk]   [32768 x 1024] fp8, 256x128 tiles
    gemm_bt8_256<1><<<dim3(8, 128, 1), 256, 0, stream>>>(
        Xt8, W8, QK8, bqk, 512, 512, 512, 1024, 0, 0, 0);

    // V in [C][N] fp8: A=Wv fp8 (rows c), B=Xt_b, bias per-row(c)
    gemm_bt8_256<2><<<dim3(8, 2, 32), 256, 0, stream>>>(
        W8 + 524288, Xt8, Vc8, bv, 512, 512, 512, 1024, 0, 524288, 524288);

    // fused attention -> H8 [B][N][C] fp8
    flash_attn<<<256, 512, 0, stream>>>(QK8, QK8 + 512, Vc8, H8);

    // out = (Wo*2^22) * H_b^T * 2^-22 + bo(row) + x   [C][N] fp32
    gemm_bt8_out<<<dim3(8, 4, 32), 256, 0, stream>>>(
        W8 + 786432, H8, out, bo, x, 512, 512, 512, 1024,
        524288, 524288, 524288, WO_INV);
}

// Round 14
// 198.409 us; speedup vs baseline: 1.1694x; 1.1694x over previous
//
#include <hip/hip_runtime.h>
#include <stdint.h>

// AttentionBlock: B=32, C=512, H=W=32 (N=1024), fp32 in/out.
//   prep (1 launch): Wq,Wk,Wv->fp8; Wo->fp8*2^22; bqk=[bq;bk]; x -> Xt fp8
//   qkv  (1 launch): QK = Xt*[Wq;Wk]^T+bqk [B*N,1024] fp8 (blocks 0-2047)
//                    V  = Wv*Xt_b^T+bv     [B][C][N]  fp8 (blocks 2048-3071)
//   flash_attn fp8 (kv64, 8 waves, PV(t)||QK(t+1) in one barrier interval)
//   out = (Wo*2^22)*H_b^T * 2^-22 + bo + x   [B][C][N] fp32 (fp8 gemm 128^2)

#define CD 512
#define NSP 1024
#define SCALE_EXP2 0.06376339f   // C^-0.5 * log2(e)
#define WO_SCALE 4194304.0f      // 2^22
#define WO_INV   2.384185791015625e-7f

using f32x4  = __attribute__((ext_vector_type(4))) float;
typedef long i64v;               // 8 x fp8 operand for MFMA

__device__ __forceinline__ unsigned char f2f8(float f) {
    unsigned int r;
    asm("v_cvt_pk_fp8_f32 %0, %1, %1" : "=v"(r) : "v"(f));
    return (unsigned char)(r & 0xffu);
}
__device__ __forceinline__ unsigned int f4_to_f8x4(float a, float b, float c, float d) {
    unsigned int r = 0;
    asm("v_cvt_pk_fp8_f32 %0, %2, %3\n\t"
        "v_cvt_pk_fp8_f32 %0, %4, %5 op_sel:[0,0,1]"
        : "=v"(r) : "0"(r), "v"(a), "v"(b), "v"(c), "v"(d));
    return r;
}
__device__ __forceinline__ void gl_lds16(const void* g, void* l) {
    __builtin_amdgcn_global_load_lds(
        (const __attribute__((address_space(1))) void*)g,
        (__attribute__((address_space(3))) void*)l, 16, 0, 0);
}

// Merged preprocess: blocks [0,4096) convert weights (Wo scaled 2^22) + bqk;
// blocks [4096,20480) transpose x [B][C][N] f32 -> Xt [B][N][C] fp8.
__global__ __launch_bounds__(256) void prep(
    const float* __restrict__ Wq, const float* __restrict__ Wk,
    const float* __restrict__ Wv, const float* __restrict__ Wo,
    const float* __restrict__ bq, const float* __restrict__ bk,
    const float* __restrict__ x,
    unsigned char* __restrict__ w8, float* __restrict__ bqk,
    unsigned char* __restrict__ xt)
{
    const int bid = blockIdx.x;
    const int tid = threadIdx.x;
    if (bid < 4096) {
        int idx = bid * 256 + tid;                // 0..1048575
        int which = idx >> 18, off = idx & 262143;
        const float* src = which == 0 ? Wq : which == 1 ? Wk : which == 2 ? Wv : Wo;
        float v = src[off] * (which == 3 ? WO_SCALE : 1.0f);
        w8[idx] = f2f8(v);
        if (idx < 1024) bqk[idx] = (idx < 512) ? bq[idx] : bk[idx - 512];
    } else {
        __shared__ float t[32][33];
        int tb = bid - 4096;                      // 0..16383
        int n0 = (tb & 31) * 32;
        int c0 = ((tb >> 5) & 15) * 32;
        int b  = tb >> 9;
        const float* xb = x + (size_t)b * CD * NSP;
        unsigned char* xtb = xt + (size_t)b * NSP * CD;
        int tx = tid & 31, ty = tid >> 5;
        #pragma unroll
        for (int i = 0; i < 4; ++i)
            t[ty + i * 8][tx] = xb[(size_t)(c0 + ty + i * 8) * NSP + n0 + tx];
        __syncthreads();
        #pragma unroll
        for (int i = 0; i < 4; ++i)
            xtb[(size_t)(n0 + ty + i * 8) * CD + c0 + tx] = f2f8(t[tx][ty + i * 8]);
    }
}

// Merged QK + V projection gemm. 128x128 tile, BK=64, K=512, 4 waves, dbuf
// gl_lds16 staging, counted vmcnt. Blocks [0,2048): QK = Xt*W^T+bqk[col].
// Blocks [2048,3072): V = Wv*Xt_b^T+bv[row]. Both write fp8, ldc=1024.
__global__ __launch_bounds__(256)
void gemm_qkv(const unsigned char* __restrict__ Xt8,
              const unsigned char* __restrict__ W8,
              unsigned char* __restrict__ QK8,
              unsigned char* __restrict__ Vc8,
              const float* __restrict__ bqk,
              const float* __restrict__ bv)
{
    __shared__ __align__(16) unsigned char As[2][128 * 64];
    __shared__ __align__(16) unsigned char Bs[2][128 * 64];

    const int bid = blockIdx.x;
    const unsigned char *Ab, *Bb;
    unsigned char* Cp;
    const float* bias;
    int biasCol;                                 // 1: bias[col], 0: bias[row]
    if (bid < 2048) {                            // QK
        int bx = bid & 7, by = bid >> 3;
        Ab = Xt8 + (size_t)by * 128 * 512;
        Bb = W8 + (size_t)bx * 128 * 512;
        Cp = QK8 + (size_t)by * 128 * 1024 + bx * 128;
        bias = bqk + bx * 128;
        biasCol = 1;
    } else {                                     // V
        int t2 = bid - 2048;
        int bx = t2 & 7, by = (t2 >> 3) & 3, z = t2 >> 5;
        Ab = W8 + 524288 + (size_t)by * 128 * 512;
        Bb = Xt8 + (size_t)z * 524288 + (size_t)bx * 128 * 512;
        Cp = Vc8 + (size_t)z * 524288 + (size_t)by * 128 * 1024 + bx * 128;
        bias = bv + by * 128;
        biasCol = 0;
    }

    const int t = threadIdx.x;
    const int lane = t & 63;
    const int wave = t >> 6;
    const int wr = wave >> 1, wc = wave & 1;
    const int lr = lane & 15, lk = lane >> 4;

    f32x4 acc[4][4] = {};

    auto stage = [&](int kt, int buf) {
        int k0 = kt << 6;
        #pragma unroll
        for (int i = 0; i < 2; ++i) {
            int rb = i * 64 + wave * 16;
            int row = rb + (lane >> 2);
            int src = (lane & 3) ^ ((row >> 1) & 3);
            gl_lds16(Ab + (size_t)row * 512 + k0 + src * 16, &As[buf][rb * 64]);
            gl_lds16(Bb + (size_t)row * 512 + k0 + src * 16, &Bs[buf][rb * 64]);
        }
    };
    stage(0, 0);
    for (int kt = 0; kt < 8; ++kt) {
        int cur = kt & 1;
        if (kt < 7) {
            stage(kt + 1, cur ^ 1);
            asm volatile("s_waitcnt vmcnt(4)" ::: "memory");
        } else {
            asm volatile("s_waitcnt vmcnt(0)" ::: "memory");
        }
        __builtin_amdgcn_s_barrier();
        const unsigned char* Ac = &As[cur][0];
        const unsigned char* Bc = &Bs[cur][0];
        #pragma unroll
        for (int kk = 0; kk < 2; ++kk) {
            int c16 = kk * 2 + (lk >> 1);
            int half = (lk & 1) * 8;
            i64v af[4], bfr[4];
            #pragma unroll
            for (int f = 0; f < 4; ++f) {
                int arow = wr * 64 + f * 16 + lr;
                af[f] = *(const i64v*)&Ac[arow * 64 + ((c16 ^ ((arow >> 1) & 3)) << 4) + half];
                int brow = wc * 64 + f * 16 + lr;
                bfr[f] = *(const i64v*)&Bc[brow * 64 + ((c16 ^ ((brow >> 1) & 3)) << 4) + half];
            }
            #pragma unroll
            for (int fm = 0; fm < 4; ++fm)
                #pragma unroll
                for (int fn = 0; fn < 4; ++fn)
                    acc[fm][fn] = __builtin_amdgcn_mfma_f32_16x16x32_fp8_fp8(
                        af[fm], bfr[fn], acc[fm][fn], 0, 0, 0);
        }
        asm volatile("s_waitcnt lgkmcnt(0)" ::: "memory");
        __builtin_amdgcn_s_barrier();
    }

    #pragma unroll
    for (int fm = 0; fm < 4; ++fm) {
        #pragma unroll
        for (int fn = 0; fn < 4; ++fn) {
            int col = wc * 64 + fn * 16 + lr;               // D col = lane&15
            int rowb = wr * 64 + fm * 16 + lk * 4;          // D row = 4*(lane>>4)+j
            #pragma unroll
            for (int j = 0; j < 4; ++j) {
                int row = rowb + j;
                float v = acc[fm][fn][j] + (biasCol ? bias[col] : bias[row]);
                Cp[(size_t)row * 1024 + col] = f2f8(v);
            }
        }
    }
}

// fp8 GEMM: C[m][n] = alpha*sum_k A[m][k]*B[n][k] (+bias) (+resid).
// 128x128 tile, BK=64, 4 waves, dbuf gl_lds16 staging, counted vmcnt.
template<int BIAS_MODE, bool RESID, bool OUT_F32>
__global__ __launch_bounds__(256)
void gemm_bt8(const unsigned char* __restrict__ A,
              const unsigned char* __restrict__ B,
              void* __restrict__ Cv,
              const float* __restrict__ bias,
              const float* __restrict__ resid,
              int K, int lda, int ldb, int ldc,
              long sA, long sB, long sC, long sR, float alpha)
{
    __shared__ __align__(16) unsigned char As[2][128 * 64];
    __shared__ __align__(16) unsigned char Bs[2][128 * 64];

    const int z = blockIdx.z;
    const unsigned char* Ab = A + (size_t)z * sA + (size_t)blockIdx.y * 128 * lda;
    const unsigned char* Bb = B + (size_t)z * sB + (size_t)blockIdx.x * 128 * ldb;

    const int t = threadIdx.x;
    const int lane = t & 63;
    const int wave = t >> 6;
    const int wr = wave >> 1, wc = wave & 1;
    const int lr = lane & 15, lk = lane >> 4;

    f32x4 acc[4][4] = {};

    const int KT = K >> 6;
    auto stage = [&](int kt, int buf) {
        int k0 = kt << 6;
        #pragma unroll
        for (int i = 0; i < 2; ++i) {
            int rb = i * 64 + wave * 16;
            int row = rb + (lane >> 2);
            int src = (lane & 3) ^ ((row >> 1) & 3);
            gl_lds16(Ab + (size_t)row * lda + k0 + src * 16, &As[buf][rb * 64]);
            gl_lds16(Bb + (size_t)row * ldb + k0 + src * 16, &Bs[buf][rb * 64]);
        }
    };
    stage(0, 0);
    for (int kt = 0; kt < KT; ++kt) {
        int cur = kt & 1;
        if (kt + 1 < KT) {
            stage(kt + 1, cur ^ 1);
            asm volatile("s_waitcnt vmcnt(4)" ::: "memory");
        } else {
            asm volatile("s_waitcnt vmcnt(0)" ::: "memory");
        }
        __builtin_amdgcn_s_barrier();
        const unsigned char* Ac = &As[cur][0];
        const unsigned char* Bc = &Bs[cur][0];
        #pragma unroll
        for (int kk = 0; kk < 2; ++kk) {
            int c16 = kk * 2 + (lk >> 1);
            int half = (lk & 1) * 8;
            i64v af[4], bfr[4];
            #pragma unroll
            for (int f = 0; f < 4; ++f) {
                int arow = wr * 64 + f * 16 + lr;
                af[f] = *(const i64v*)&Ac[arow * 64 + ((c16 ^ ((arow >> 1) & 3)) << 4) + half];
                int brow = wc * 64 + f * 16 + lr;
                bfr[f] = *(const i64v*)&Bc[brow * 64 + ((c16 ^ ((brow >> 1) & 3)) << 4) + half];
            }
            #pragma unroll
            for (int fm = 0; fm < 4; ++fm)
                #pragma unroll
                for (int fn = 0; fn < 4; ++fn)
                    acc[fm][fn] = __builtin_amdgcn_mfma_f32_16x16x32_fp8_fp8(
                        af[fm], bfr[fn], acc[fm][fn], 0, 0, 0);
        }
        asm volatile("s_waitcnt lgkmcnt(0)" ::: "memory");
        __builtin_amdgcn_s_barrier();
    }

    const int m0 = blockIdx.y * 128;
    const int n0 = blockIdx.x * 128;
    unsigned char* C8 = (unsigned char*)Cv + (size_t)z * sC;
    float* Cf = (float*)Cv + (size_t)z * sC;
    const float* rp = RESID ? resid + (size_t)z * sR : nullptr;
    #pragma unroll
    for (int fm = 0; fm < 4; ++fm) {
        #pragma unroll
        for (int fn = 0; fn < 4; ++fn) {
            int col = n0 + wc * 64 + fn * 16 + lr;          // D col = lane&15
            int rowb = m0 + wr * 64 + fm * 16 + lk * 4;     // D row = 4*(lane>>4)+j
            #pragma unroll
            for (int j = 0; j < 4; ++j) {
                int row = rowb + j;
                float v = acc[fm][fn][j] * alpha;
                if (BIAS_MODE == 1) v += bias[col];
                if (BIAS_MODE == 2) v += bias[row];
                if (RESID) v += rp[(size_t)row * ldc + col];
                if (OUT_F32) Cf[(size_t)row * ldc + col] = v;
                else         C8[(size_t)row * ldc + col] = f2f8(v);
            }
        }
    }
}

// Fused attention, fp8, kv-tile 64, 8 waves (512 thr), grid 256.
// Software-pipelined: per iteration t the single barrier interval contains
//   [rescale + PV(t) from Ps[t&1],Vs[t&1]]  then  [QK(t+1) from Ks[(t+1)&1]]
//   then softmax(t+1) -> Ps[(t+1)&1].
// PV(t) is independent of softmax(t+1); the compiler co-schedules the two
// MFMA streams within the interval (manual interleave spills - R13).
__global__ __launch_bounds__(512, 2)
void flash_attn(const unsigned char* __restrict__ Q,
                const unsigned char* __restrict__ Kg,
                const unsigned char* __restrict__ Vg,
                unsigned char* __restrict__ H)
{
    __shared__ __align__(16) unsigned char Ks[2][64 * 512];  // 64 KB
    __shared__ __align__(16) unsigned char Vs[2][512 * 64];  // 64 KB
    __shared__ __align__(16) unsigned char Ps[2][128 * 72];  // 18 KB
    __shared__ __align__(16) float Ls[2][128];
    __shared__ int flags[2];                                 // rescale epoch

    const int p = blockIdx.x;                // XCD-affinity decode
    const int b  = ((p >> 6) << 3) + (p & 7);
    const int qt = (p >> 3) & 7;

    const int tid = threadIdx.x;
    const int w = tid >> 6, lane = tid & 63;
    const int lr = lane & 15, lk = lane >> 4;
    const int q0 = qt * 128 + w * 16;

    // Q frags (B-operand): lane holds Q[q0+lr][st*32 + lk*8 + e], fp8
    i64v qf[16];
    const unsigned char* qp = Q + ((size_t)b * NSP + q0 + lr) * 1024 + lk * 8;
    #pragma unroll
    for (int st = 0; st < 16; ++st) qf[st] = *(const i64v*)(qp + st * 32);

    f32x4 o[8][4] = {};          // [qf2][cf]: q = qf2*16+4lk+j, c = w*64+cf*16+lr
    float m = -3.0e38f, l = 0.f;

    const unsigned char* Kb = Kg + (size_t)b * NSP * 1024;   // rows 1024B (Q|K)
    const unsigned char* Vb = Vg + (size_t)b * CD * 1024;

    auto stageK = [&](int t, int buf) {      // 64 rows x 512B; 8 rows/wave
        int kv0 = t * 64;
        #pragma unroll
        for (int i = 0; i < 4; ++i) {
            int rb = i * 16 + w * 2;
            int row = rb + (lane >> 5);
            int src = (lane & 31) ^ (row & 7);
            gl_lds16(Kb + (size_t)(kv0 + row) * 1024 + src * 16, &Ks[buf][rb * 512]);
        }
    };
    auto stageV = [&](int t, int buf) {      // 512 rows x 64B; 64 rows/wave
        int kv0 = t * 64;
        #pragma unroll
        for (int i = 0; i < 4; ++i) {
            int cb = i * 128 + w * 16;
            int c = cb + (lane >> 2);
            int src = (lane & 3) ^ ((c >> 1) & 3);
            gl_lds16(Vb + (size_t)c * 1024 + kv0 + src * 16, &Vs[buf][cb * 64]);
        }
    };

    // QK^T + softmax for tile tau -> Ps[tau&1]. S^T[kv][q=lr], kv=kvf*16+4lk+j.
    auto qksm = [&](int tau) {
        const int pb = tau & 1;
        const unsigned char* Kc = &Ks[pb][0];
        f32x4 s[4] = {};
        __builtin_amdgcn_s_setprio(1);
        #pragma unroll
        for (int st = 0; st < 16; ++st) {
            int c16 = st * 2 + (lk >> 1);
            int half = (lk & 1) * 8;
            #pragma unroll
            for (int kvf = 0; kvf < 4; ++kvf) {
                int row = kvf * 16 + lr;
                i64v kf = *(const i64v*)&Kc[row * 512 + ((c16 ^ (row & 7)) << 4) + half];
                s[kvf] = __builtin_amdgcn_mfma_f32_16x16x32_fp8_fp8(kf, qf[st], s[kvf], 0, 0, 0);
            }
        }
        __builtin_amdgcn_s_setprio(0);
        #pragma unroll
        for (int kvf = 0; kvf < 4; ++kvf)
            #pragma unroll
            for (int j = 0; j < 4; ++j) s[kvf][j] *= SCALE_EXP2;

        float pm = fmaxf(fmaxf(fmaxf(s[0][0], s[0][1]), fmaxf(s[0][2], s[0][3])),
                         fmaxf(fmaxf(s[1][0], s[1][1]), fmaxf(s[1][2], s[1][3])));
        pm = fmaxf(pm, fmaxf(fmaxf(fmaxf(s[2][0], s[2][1]), fmaxf(s[2][2], s[2][3])),
                             fmaxf(fmaxf(s[3][0], s[3][1]), fmaxf(s[3][2], s[3][3]))));
        pm = fmaxf(pm, __shfl_xor(pm, 16));
        pm = fmaxf(pm, __shfl_xor(pm, 32));
        bool ev = !__all(pm - m <= 8.0f);       // defer-max: P <= 2^8 < 448
        float mn = fmaxf(m, pm);
        float sc = ev ? exp2f(m - mn) : 1.0f;
        if (ev) { m = mn; l *= sc; }
        if (lk == 0) Ls[pb][w * 16 + lr] = sc;
        if (ev && lane == 0) flags[pb] = tau;   // epoch flag

        float rs = 0.f;
        #pragma unroll
        for (int kvf = 0; kvf < 4; ++kvf)
            #pragma unroll
            for (int j = 0; j < 4; ++j) {
                s[kvf][j] = exp2f(s[kvf][j] - m);
                rs += s[kvf][j];
            }
        rs += __shfl_xor(rs, 16);
        rs += __shfl_xor(rs, 32);
        l += rs;

        #pragma unroll
        for (int kvf = 0; kvf < 4; ++kvf) {
            unsigned int pk = f4_to_f8x4(s[kvf][0], s[kvf][1], s[kvf][2], s[kvf][3]);
            *(unsigned int*)&Ps[pb][(w * 16 + lr) * 72 + kvf * 16 + lk * 4] = pk;
        }
    };

    if (tid == 0) { flags[0] = -1; flags[1] = -1; }
    stageK(0, 0); stageV(0, 0);
    asm volatile("s_waitcnt vmcnt(0) lgkmcnt(0)" ::: "memory");
    __builtin_amdgcn_s_barrier();
    stageK(1, 1);
    qksm(0);                                    // P(0) -> Ps[0]
    asm volatile("s_waitcnt vmcnt(0) lgkmcnt(0)" ::: "memory");
    __builtin_amdgcn_s_barrier();               // P(0) visible; K(1) landed

    for (int t = 0; t < 16; ++t) {
        const int cur = t & 1;
        if (t < 14) stageK(t + 2, cur);         // Ks[cur]: readers drained at t-1
        if (t < 15) stageV(t + 1, cur ^ 1);     // Vs[cur^1]: readers drained at t-1

        // ---- rescale + PV(t): wave owns c-slice [w*64,(w+1)*64), all 128 q ----
        if (flags[cur] == t) {
            #pragma unroll
            for (int qf2 = 0; qf2 < 8; ++qf2) {
                f32x4 scv = *(const f32x4*)&Ls[cur][qf2 * 16 + lk * 4];
                #pragma unroll
                for (int cf = 0; cf < 4; ++cf) {
                    o[qf2][cf][0] *= scv[0]; o[qf2][cf][1] *= scv[1];
                    o[qf2][cf][2] *= scv[2]; o[qf2][cf][3] *= scv[3];
                }
            }
        }
        const unsigned char* Vc = &Vs[cur][0];
        __builtin_amdgcn_s_setprio(1);
        #pragma unroll
        for (int ks = 0; ks < 2; ++ks) {
            int c16 = ks * 2 + (lk >> 1);
            int half = (lk & 1) * 8;
            i64v vfr[4];
            #pragma unroll
            for (int cf = 0; cf < 4; ++cf) {
                int c = w * 64 + cf * 16 + lr;
                vfr[cf] = *(const i64v*)&Vc[c * 64 + ((c16 ^ ((c >> 1) & 3)) << 4) + half];
            }
            #pragma unroll
            for (int qf2 = 0; qf2 < 8; ++qf2) {
                i64v pa = *(const i64v*)&Ps[cur][(qf2 * 16 + lr) * 72 + ks * 32 + lk * 8];
                #pragma unroll
                for (int cf = 0; cf < 4; ++cf)
                    o[qf2][cf] = __builtin_amdgcn_mfma_f32_16x16x32_fp8_fp8(
                        pa, vfr[cf], o[qf2][cf], 0, 0, 0);
            }
        }
        __builtin_amdgcn_s_setprio(0);

        // ---- QK(t+1) + softmax(t+1) -> Ps[cur^1] ----
        if (t < 15) qksm(t + 1);

        asm volatile("s_waitcnt vmcnt(0) lgkmcnt(0)" ::: "memory");
        __builtin_amdgcn_s_barrier();
    }

    // epilogue: 1/l per q-row via Ls[0], write H fp8
    if (lk == 0) Ls[0][w * 16 + lr] = 1.0f / l;
    asm volatile("s_waitcnt lgkmcnt(0)" ::: "memory");
    __builtin_amdgcn_s_barrier();
    unsigned char* Hp = H + ((size_t)b * NSP + qt * 128) * CD + w * 64;
    #pragma unroll
    for (int qf2 = 0; qf2 < 8; ++qf2) {
        f32x4 li = *(const f32x4*)&Ls[0][qf2 * 16 + lk * 4];
        #pragma unroll
        for (int cf = 0; cf < 4; ++cf) {
            #pragma unroll
            for (int j = 0; j < 4; ++j)
                Hp[(size_t)(qf2 * 16 + lk * 4 + j) * CD + cf * 16 + lr] =
                    f2f8(o[qf2][cf][j] * li[j]);
        }
    }
}

extern "C" void kernel_launch(void* const* d_in, const int* in_sizes, int n_in,
                              void* d_out, int out_size, void* d_ws, size_t ws_size,
                              hipStream_t stream)
{
    const float* x  = (const float*)d_in[0];
    const float* Wq = (const float*)d_in[1];
    const float* bq = (const float*)d_in[2];
    const float* Wk = (const float*)d_in[3];
    const float* bk = (const float*)d_in[4];
    const float* Wv = (const float*)d_in[5];
    const float* bv = (const float*)d_in[6];
    const float* Wo = (const float*)d_in[7];
    const float* bo = (const float*)d_in[8];
    float* out = (float*)d_out;

    unsigned char* w = (unsigned char*)d_ws;   // byte layout, 16B-aligned
    unsigned char* W8  = w;                     // Wq|Wk|Wv|Wo(x2^22) fp8, 1 MB
    float*         bqk = (float*)(w + 1048576); // 4 KB
    unsigned char* Xt8 = w + 1052672;           // [B][N][C] fp8, 16 MB
    unsigned char* QK8 = w + 17829888;          // [B][N][1024] fp8, 32 MB
    unsigned char* Vc8 = w + 51384320;          // [B][C][N] fp8, 16 MB
    unsigned char* H8  = w + 68161536;          // [B][N][C] fp8, 16 MB

    // prep: weights->fp8 (+bqk) and x->Xt8 in one launch
    prep<<<20480, 256, 0, stream>>>(Wq, Wk, Wv, Wo, bq, bk, x, W8, bqk, Xt8);

    // QK [32768x1024] and V [B][C][N] in one launch (3072 blocks)
    gemm_qkv<<<3072, 256, 0, stream>>>(Xt8, W8, QK8, Vc8, bqk, bv);

    // fused attention -> H8 [B][N][C] fp8
    flash_attn<<<256, 512, 0, stream>>>(QK8, QK8 + 512, Vc8, H8);

    // out = (Wo*2^22) * H_b^T * 2^-22 + bo(row) + x   [C][N] fp32
    gemm_bt8<2, true, true><<<dim3(8, 4, 32), 256, 0, stream>>>(
        W8 + 786432, H8, out, bo, x, 512, 512, 512, 1024,
        0, 524288, 524288, 524288, WO_INV);
}